// Round 10
// baseline (132.347 us; speedup 1.0000x reference)
//
#include <hip/hip_runtime.h>
#include <hip/hip_bf16.h>

// Problem constants
#define NF  200
#define DIN 3
#define NH  15
#define NE  30
#define NB  32768

typedef __attribute__((ext_vector_type(8)))  short short8;
typedef __attribute__((ext_vector_type(16))) float f32x16;

constexpr int FSPLIT = 10;           // feature split across grid.y
constexpr int FPW    = NF / FSPLIT;  // 20 features per block-slice -> 10 pairs
constexpr int PAIRS  = FPW / 2;      // 10
constexpr int NBATCH = FPW / 4;      // 5 y-load batches (4 features = 3 float4)
constexpr int BT     = 512;          // threads per block (8 waves)
constexpr int RPW    = 32;           // rows per wave (one 32x32 MFMA tile)
constexpr int RPB    = 8 * RPW;      // 256 rows per block -> grid.x = 128

// ws layout:
// A1P : [100][64][8 bf16] pair-packed layer-1 A-frag            @ 0       (102400 B)
//        rows 0-15: feat 2p {w0,w1,w2,b1} in k0-3; rows 16-31: feat 2p+1 in k4-7
// W2Q : [200][64][8 bf16] layer-2 B-frag, k-map h=crow(j,hi), b2@k15  @ 102400 (204800 B)
// W3Q : [100][32][2 f32]  {w3[2p][e], w3[2p+1][e]} pair-packed  @ 307200 (25600 B)
constexpr size_t OFF_A1P = 0;
constexpr size_t OFF_W2Q = 102400;
constexpr size_t OFF_W3Q = 307200;

__device__ __forceinline__ unsigned f2bfu(float x) {
    __hip_bfloat16 h = __float2bfloat16(x);
    unsigned short u; __builtin_memcpy(&u, &h, 2); return (unsigned)u;
}

// HW packed convert: lo -> D[15:0], hi -> D[31:16], RNE (same as __float2bfloat16)
__device__ __forceinline__ unsigned cvtpk(float lo, float hi) {
    unsigned r;
    asm("v_cvt_pk_bf16_f32 %0, %1, %2" : "=v"(r) : "v"(lo), "v"(hi));
    return r;
}

__global__ void nn_init(float* __restrict__ out, const float* __restrict__ b3) {
    int i = blockIdx.x * 256 + threadIdx.x;
    if (i < NB) out[i] = b3[0];
}

__global__ void nn_prep(const float* __restrict__ W1, const float* __restrict__ b1,
                        const float* __restrict__ W2, const float* __restrict__ b2,
                        const float* __restrict__ W3, char* __restrict__ ws) {
    const int f = blockIdx.x;
    const int t = threadIdx.x;      // 64
    const int x = t & 31, hi = t >> 5;
    unsigned short* A1p = (unsigned short*)(ws + OFF_A1P);
    unsigned short* W2q = (unsigned short*)(ws + OFF_W2Q);
    float*          w3q = (float*)(ws + OFF_W3Q);

    // ---- W2 B-fragment, permuted k-map; h==15 slot carries b2 ----
    {
        unsigned short* d = W2q + ((size_t)f * 64 + t) * 8;
#pragma unroll
        for (int j = 0; j < 8; ++j) {
            const int h = (j & 3) + 8 * (j >> 2) + 4 * hi;   // 0..15
            float v = 0.f;
            if (x < NE) v = (h < NH) ? W2[((size_t)f * NH + h) * NE + x]
                                     : b2[f * NE + x];       // h==15
            d[j] = (unsigned short)f2bfu(v);
        }
    }
    // ---- W3 pair-packed: [p][e][2] ----
    if (t < 32) {
        const float v = (t < NE) ? W3[f * NE + t] : 0.f;
        w3q[(((size_t)(f >> 1) * 32) + t) * 2 + (f & 1)] = v;
    }

    // ---- pair-packed layer-1 A fragment (even f writes pair f/2) ----
    if ((f & 1) == 0) {
        unsigned short* a = A1p + ((size_t)(f >> 1) * 64 + t) * 8;
#pragma unroll
        for (int j = 0; j < 8; ++j) {
            float v = 0.f;
            if (hi == 0) {
                if (x < 16) {                    // feature f, h = x, k0-3
                    if (x < NH) {
                        if (j < 3)       v = W1[((size_t)f * DIN + j) * NH + x];
                        else if (j == 3) v = b1[f * NH + x];
                    }
                } else {                          // feature f+1, h = x-16, k4-7
                    const int h = x - 16;
                    if (h < NH) {
                        if (j >= 4 && j < 7) v = W1[((size_t)(f + 1) * DIN + (j - 4)) * NH + h];
                        else if (j == 7)     v = b1[(f + 1) * NH + h];
                    }
                }
            }
            a[j] = (unsigned short)f2bfu(v);
        }
    }
}

__global__ __launch_bounds__(BT, 6)
void nn_main(const float* __restrict__ y, const char* __restrict__ ws,
             float* __restrict__ out) {
    // LDS-staged per-block weight slice (all 8 waves share it)
    __shared__ __align__(16) short sA1[PAIRS * 512];   // 10240 B = 640 uint4
    __shared__ __align__(16) short sW2[FPW * 512];     // 20480 B = 1280 uint4
    __shared__ __align__(16) float sW3[PAIRS * 64];    //  2560 B = 160 uint4

    const int t  = threadIdx.x;
    const int w  = t >> 6;
    const int l  = t & 63;
    const int ln = l & 31;
    const int hi = l >> 5;
    const int r0 = blockIdx.x * RPB + w * RPW;
    const int f0 = blockIdx.y * FPW;
    const int p0 = f0 >> 1;

    // ---- stage weights global -> LDS (coalesced uint4 copies, BT=512) ----
    {
        const uint4* gA = (const uint4*)(ws + OFF_A1P + (size_t)p0 * 1024);
        const uint4* gW = (const uint4*)(ws + OFF_W2Q + (size_t)f0 * 1024);
        const uint4* g3 = (const uint4*)(ws + OFF_W3Q + (size_t)p0 * 256);
        uint4* dA = (uint4*)sA1;
        uint4* dW = (uint4*)sW2;
        uint4* d3 = (uint4*)sW3;
        // sA1 = 640 uint4
        dA[t] = gA[t];
        if (t < 128)  dA[512 + t] = gA[512 + t];
        // sW2 = 1280 uint4
        dW[t]       = gW[t];
        dW[t + 512] = gW[t + 512];
        if (t < 256)  dW[1024 + t] = gW[1024 + t];
        // sW3 = 160 uint4
        if (t < 160)  d3[t] = g3[t];
    }
    __syncthreads();

    // f0*3 floats = 240B*by -> 16B-aligned float4 base
    const float4* __restrict__ yp4 = reinterpret_cast<const float4*>(
        y + (size_t)(r0 + ln) * (NF * DIN) + (size_t)f0 * DIN);
    const short* __restrict__ a1l = sA1 + l * 8;
    const short* __restrict__ w2l = sW2 + l * 8;

    const unsigned himask = hi ? 0x3F800000u : 0u;   // bf16(1.0) @ k15 for hi lanes
    const float onef = 1.0f;                         // loop-invariant VGPR for cvtpk
    const f32x16 zc = {};

    float acc[16];
#pragma unroll
    for (int r = 0; r < 16; ++r) acc[r] = 0.f;

    auto pair_body = [&](int pp, float y0A, float y1A, float y2A,
                                 float y0B, float y1B, float y2B) {
        // hoist LDS weight reads to the top (scheduler overlaps with packing)
        const short8 A1  = *reinterpret_cast<const short8*>(a1l + (size_t)pp * 512);
        const short8 B2A = *reinterpret_cast<const short8*>(w2l + (size_t)(2 * pp) * 512);
        const short8 B2B = *reinterpret_cast<const short8*>(w2l + (size_t)(2 * pp + 1) * 512);
        const float2 w3v = *reinterpret_cast<const float2*>(sW3 + (pp * 32 + ln) * 2);

        // B1: k0-2 = y_A, k3 = 1, k4-6 = y_B, k7 = 1 (hi lanes' B garbage-OK: A rows zero)
        union { unsigned u[4]; short8 s; } B1;
        B1.u[0] = cvtpk(y0A, y1A);
        B1.u[1] = cvtpk(y2A, onef);
        B1.u[2] = cvtpk(y0B, y1B);
        B1.u[3] = cvtpk(y2B, onef);

        const f32x16 d1 = __builtin_amdgcn_mfma_f32_32x32x16_bf16(A1, B1.s, zc, 0, 0, 0);

        // A2 packs: regs 0-7 -> feature A, regs 8-15 -> feature B; 1.0 @ k15
        // (d1[7]/d1[15] are zero on hi lanes -> OR of bf16(1.0) is clean)
        union { unsigned u[4]; short8 s; } A2A, A2B;
#pragma unroll
        for (int i = 0; i < 4; ++i) {
            A2A.u[i] = cvtpk(fmaxf(d1[2 * i], 0.f),     fmaxf(d1[2 * i + 1], 0.f));
            A2B.u[i] = cvtpk(fmaxf(d1[8 + 2 * i], 0.f), fmaxf(d1[8 + 2 * i + 1], 0.f));
        }
        A2A.u[3] |= himask;
        A2B.u[3] |= himask;

        const f32x16 d2A = __builtin_amdgcn_mfma_f32_32x32x16_bf16(A2A.s, B2A, zc, 0, 0, 0);
#pragma unroll
        for (int r = 0; r < 16; ++r) acc[r] = fmaf(fmaxf(d2A[r], 0.f), w3v.x, acc[r]);

        const f32x16 d2B = __builtin_amdgcn_mfma_f32_32x32x16_bf16(A2B.s, B2B, zc, 0, 0, 0);
#pragma unroll
        for (int r = 0; r < 16; ++r) acc[r] = fmaf(fmaxf(d2B[r], 0.f), w3v.y, acc[r]);
    };

    // double-buffered y batches: 3 x float4 = 12 floats = 4 features = 2 pairs
    float4 c0 = yp4[0], c1 = yp4[1], c2 = yp4[2];
#pragma unroll 1
    for (int bi = 0; bi < NBATCH; ++bi) {
        float4 n0 = c0, n1 = c1, n2 = c2;
        if (bi + 1 < NBATCH) {
            n0 = yp4[3 * bi + 3];
            n1 = yp4[3 * bi + 4];
            n2 = yp4[3 * bi + 5];
        }
        pair_body(2 * bi,     c0.x, c0.y, c0.z,  c0.w, c1.x, c1.y);
        pair_body(2 * bi + 1, c1.z, c1.w, c2.x,  c2.y, c2.z, c2.w);
        c0 = n0; c1 = n1; c2 = n2;
    }

    // ---- reduce over e (32 lanes within each hi-half) ----
#pragma unroll
    for (int r = 0; r < 16; ++r) {
#pragma unroll
        for (int m = 1; m < 32; m <<= 1) acc[r] += __shfl_xor(acc[r], m);
    }
    if (ln == 0) {
#pragma unroll
        for (int r = 0; r < 16; ++r) {
            const int row = (r & 3) + 8 * (r >> 2) + 4 * hi;
            atomicAdd(&out[r0 + row], acc[r]);
        }
    }
}

extern "C" void kernel_launch(void* const* d_in, const int* in_sizes, int n_in,
                              void* d_out, int out_size, void* d_ws, size_t ws_size,
                              hipStream_t stream) {
    const float* y  = (const float*)d_in[0];
    const float* W1 = (const float*)d_in[1];
    const float* b1 = (const float*)d_in[2];
    const float* W2 = (const float*)d_in[3];
    const float* b2 = (const float*)d_in[4];
    const float* W3 = (const float*)d_in[5];
    const float* b3 = (const float*)d_in[6];
    float* out = (float*)d_out;

    nn_prep<<<dim3(NF), dim3(64), 0, stream>>>(W1, b1, W2, b2, W3, (char*)d_ws);
    nn_init<<<dim3((NB + 255) / 256), dim3(256), 0, stream>>>(out, b3);
    nn_main<<<dim3(NB / RPB, FSPLIT), dim3(BT), 0, stream>>>(
        y, (const char*)d_ws, out);
}

// Round 11
// 47.325 us; speedup vs baseline: 2.7966x; 2.7966x over previous
//
#include <hip/hip_runtime.h>
#include <hip/hip_bf16.h>

// Problem constants
#define NF  200
#define DIN 3
#define NH  15
#define NE  30
#define NB  32768

typedef __attribute__((ext_vector_type(8)))  short short8;
typedef __attribute__((ext_vector_type(16))) float f32x16;

constexpr int FSPLIT = 10;           // feature split across grid.y
constexpr int FPW    = NF / FSPLIT;  // 20 features per block-slice -> 10 pairs
constexpr int PAIRS  = FPW / 2;      // 10
constexpr int NBATCH = FPW / 4;      // 5 y-load batches (4 features = 3 float4)
constexpr int BT     = 256;          // threads per block (4 waves) -- round-9 proven
constexpr int RPW    = 32;           // rows per wave (one 32x32 MFMA tile)
constexpr int RPB    = 4 * RPW;      // 128 rows per block -> grid.x = 256

// ws layout:
// A1P : [100][64][8 bf16] pair-packed layer-1 A-frag            @ 0       (102400 B)
//        rows 0-15: feat 2p {w0,w1,w2,b1} in k0-3; rows 16-31: feat 2p+1 in k4-7
// W2Q : [200][64][8 bf16] layer-2 B-frag, k-map h=crow(j,hi), b2@k15  @ 102400 (204800 B)
// W3Q : [100][32][2 f32]  {w3[2p][e], w3[2p+1][e]} pair-packed  @ 307200 (25600 B)
constexpr size_t OFF_A1P = 0;
constexpr size_t OFF_W2Q = 102400;
constexpr size_t OFF_W3Q = 307200;

__device__ __forceinline__ unsigned f2bfu(float x) {
    __hip_bfloat16 h = __float2bfloat16(x);
    unsigned short u; __builtin_memcpy(&u, &h, 2); return (unsigned)u;
}

// HW packed convert: lo -> D[15:0], hi -> D[31:16], RNE (same as __float2bfloat16)
__device__ __forceinline__ unsigned cvtpk(float lo, float hi) {
    unsigned r;
    asm("v_cvt_pk_bf16_f32 %0, %1, %2" : "=v"(r) : "v"(lo), "v"(hi));
    return r;
}

__global__ void nn_init(float* __restrict__ out, const float* __restrict__ b3) {
    int i = blockIdx.x * 256 + threadIdx.x;
    if (i < NB) out[i] = b3[0];
}

__global__ void nn_prep(const float* __restrict__ W1, const float* __restrict__ b1,
                        const float* __restrict__ W2, const float* __restrict__ b2,
                        const float* __restrict__ W3, char* __restrict__ ws) {
    const int f = blockIdx.x;
    const int t = threadIdx.x;      // 64
    const int x = t & 31, hi = t >> 5;
    unsigned short* A1p = (unsigned short*)(ws + OFF_A1P);
    unsigned short* W2q = (unsigned short*)(ws + OFF_W2Q);
    float*          w3q = (float*)(ws + OFF_W3Q);

    // ---- W2 B-fragment, permuted k-map; h==15 slot carries b2 ----
    {
        unsigned short* d = W2q + ((size_t)f * 64 + t) * 8;
#pragma unroll
        for (int j = 0; j < 8; ++j) {
            const int h = (j & 3) + 8 * (j >> 2) + 4 * hi;   // 0..15
            float v = 0.f;
            if (x < NE) v = (h < NH) ? W2[((size_t)f * NH + h) * NE + x]
                                     : b2[f * NE + x];       // h==15
            d[j] = (unsigned short)f2bfu(v);
        }
    }
    // ---- W3 pair-packed: [p][e][2] ----
    if (t < 32) {
        const float v = (t < NE) ? W3[f * NE + t] : 0.f;
        w3q[(((size_t)(f >> 1) * 32) + t) * 2 + (f & 1)] = v;
    }

    // ---- pair-packed layer-1 A fragment (even f writes pair f/2) ----
    if ((f & 1) == 0) {
        unsigned short* a = A1p + ((size_t)(f >> 1) * 64 + t) * 8;
#pragma unroll
        for (int j = 0; j < 8; ++j) {
            float v = 0.f;
            if (hi == 0) {
                if (x < 16) {                    // feature f, h = x, k0-3
                    if (x < NH) {
                        if (j < 3)       v = W1[((size_t)f * DIN + j) * NH + x];
                        else if (j == 3) v = b1[f * NH + x];
                    }
                } else {                          // feature f+1, h = x-16, k4-7
                    const int h = x - 16;
                    if (h < NH) {
                        if (j >= 4 && j < 7) v = W1[((size_t)(f + 1) * DIN + (j - 4)) * NH + h];
                        else if (j == 7)     v = b1[(f + 1) * NH + h];
                    }
                }
            }
            a[j] = (unsigned short)f2bfu(v);
        }
    }
}

__global__ __launch_bounds__(BT, 4)
void nn_main(const float* __restrict__ y, const char* __restrict__ ws,
             float* __restrict__ out) {
    // LDS-staged per-block weight slice (all 4 waves share it)
    __shared__ __align__(16) short sA1[PAIRS * 512];   // 10240 B = 640 uint4
    __shared__ __align__(16) short sW2[FPW * 512];     // 20480 B = 1280 uint4
    __shared__ __align__(16) float sW3[PAIRS * 64];    //  2560 B = 160 uint4

    const int t  = threadIdx.x;
    const int w  = t >> 6;
    const int l  = t & 63;
    const int ln = l & 31;
    const int hi = l >> 5;
    const int r0 = blockIdx.x * RPB + w * RPW;
    const int f0 = blockIdx.y * FPW;
    const int p0 = f0 >> 1;

    // ---- stage weights global -> LDS (coalesced uint4 copies, BT=256) ----
    {
        const uint4* gA = (const uint4*)(ws + OFF_A1P + (size_t)p0 * 1024);
        const uint4* gW = (const uint4*)(ws + OFF_W2Q + (size_t)f0 * 1024);
        const uint4* g3 = (const uint4*)(ws + OFF_W3Q + (size_t)p0 * 256);
        uint4* dA = (uint4*)sA1;
        uint4* dW = (uint4*)sW2;
        uint4* d3 = (uint4*)sW3;
        // sA1 = 640 uint4: 2 full rounds (0..511) + guarded partial (512..639)
#pragma unroll
        for (int i = 0; i < 2; ++i)  dA[t + 256 * i] = gA[t + 256 * i];
        if (t + 512 < 640)           dA[t + 512]     = gA[t + 512];
        // sW2 = 1280 uint4: 5 full rounds
#pragma unroll
        for (int i = 0; i < 5; ++i)  dW[t + 256 * i] = gW[t + 256 * i];
        // sW3 = 160 uint4
        if (t < 160)                 d3[t]           = g3[t];
    }
    __syncthreads();

    // f0*3 floats = 240B*by -> 16B-aligned float4 base
    const float4* __restrict__ yp4 = reinterpret_cast<const float4*>(
        y + (size_t)(r0 + ln) * (NF * DIN) + (size_t)f0 * DIN);
    const short* __restrict__ a1l = sA1 + l * 8;
    const short* __restrict__ w2l = sW2 + l * 8;

    const unsigned himask = hi ? 0x3F800000u : 0u;   // bf16(1.0) @ k15 for hi lanes
    const float onef = 1.0f;                         // loop-invariant VGPR for cvtpk
    const f32x16 zc = {};

    float acc[16];
#pragma unroll
    for (int r = 0; r < 16; ++r) acc[r] = 0.f;

    auto pair_body = [&](int pp, float y0A, float y1A, float y2A,
                                 float y0B, float y1B, float y2B) {
        // hoist LDS weight reads to the top (scheduler overlaps with packing)
        const short8 A1  = *reinterpret_cast<const short8*>(a1l + (size_t)pp * 512);
        const short8 B2A = *reinterpret_cast<const short8*>(w2l + (size_t)(2 * pp) * 512);
        const short8 B2B = *reinterpret_cast<const short8*>(w2l + (size_t)(2 * pp + 1) * 512);
        const float2 w3v = *reinterpret_cast<const float2*>(sW3 + (pp * 32 + ln) * 2);

        // B1: k0-2 = y_A, k3 = 1, k4-6 = y_B, k7 = 1 (hi lanes' B garbage-OK: A rows zero)
        union { unsigned u[4]; short8 s; } B1;
        B1.u[0] = cvtpk(y0A, y1A);
        B1.u[1] = cvtpk(y2A, onef);
        B1.u[2] = cvtpk(y0B, y1B);
        B1.u[3] = cvtpk(y2B, onef);

        const f32x16 d1 = __builtin_amdgcn_mfma_f32_32x32x16_bf16(A1, B1.s, zc, 0, 0, 0);

        // A2 packs: regs 0-7 -> feature A, regs 8-15 -> feature B; 1.0 @ k15
        union { unsigned u[4]; short8 s; } A2A, A2B;
#pragma unroll
        for (int i = 0; i < 4; ++i) {
            A2A.u[i] = cvtpk(fmaxf(d1[2 * i], 0.f),     fmaxf(d1[2 * i + 1], 0.f));
            A2B.u[i] = cvtpk(fmaxf(d1[8 + 2 * i], 0.f), fmaxf(d1[8 + 2 * i + 1], 0.f));
        }
        A2A.u[3] |= himask;
        A2B.u[3] |= himask;

        const f32x16 d2A = __builtin_amdgcn_mfma_f32_32x32x16_bf16(A2A.s, B2A, zc, 0, 0, 0);
#pragma unroll
        for (int r = 0; r < 16; ++r) acc[r] = fmaf(fmaxf(d2A[r], 0.f), w3v.x, acc[r]);

        const f32x16 d2B = __builtin_amdgcn_mfma_f32_32x32x16_bf16(A2B.s, B2B, zc, 0, 0, 0);
#pragma unroll
        for (int r = 0; r < 16; ++r) acc[r] = fmaf(fmaxf(d2B[r], 0.f), w3v.y, acc[r]);
    };

    // double-buffered y batches: 3 x float4 = 12 floats = 4 features = 2 pairs
    float4 c0 = yp4[0], c1 = yp4[1], c2 = yp4[2];
#pragma unroll 1
    for (int bi = 0; bi < NBATCH; ++bi) {
        float4 n0 = c0, n1 = c1, n2 = c2;
        if (bi + 1 < NBATCH) {
            n0 = yp4[3 * bi + 3];
            n1 = yp4[3 * bi + 4];
            n2 = yp4[3 * bi + 5];
        }
        pair_body(2 * bi,     c0.x, c0.y, c0.z,  c0.w, c1.x, c1.y);
        pair_body(2 * bi + 1, c1.z, c1.w, c2.x,  c2.y, c2.z, c2.w);
        c0 = n0; c1 = n1; c2 = n2;
    }

    // ---- reduce over e (32 lanes within each hi-half) ----
#pragma unroll
    for (int r = 0; r < 16; ++r) {
#pragma unroll
        for (int m = 1; m < 32; m <<= 1) acc[r] += __shfl_xor(acc[r], m);
    }
    if (ln == 0) {
#pragma unroll
        for (int r = 0; r < 16; ++r) {
            const int row = (r & 3) + 8 * (r >> 2) + 4 * hi;
            atomicAdd(&out[r0 + row], acc[r]);
        }
    }
}

extern "C" void kernel_launch(void* const* d_in, const int* in_sizes, int n_in,
                              void* d_out, int out_size, void* d_ws, size_t ws_size,
                              hipStream_t stream) {
    const float* y  = (const float*)d_in[0];
    const float* W1 = (const float*)d_in[1];
    const float* b1 = (const float*)d_in[2];
    const float* W2 = (const float*)d_in[3];
    const float* b2 = (const float*)d_in[4];
    const float* W3 = (const float*)d_in[5];
    const float* b3 = (const float*)d_in[6];
    float* out = (float*)d_out;

    nn_prep<<<dim3(NF), dim3(64), 0, stream>>>(W1, b1, W2, b2, W3, (char*)d_ws);
    nn_init<<<dim3((NB + 255) / 256), dim3(256), 0, stream>>>(out, b3);
    nn_main<<<dim3(NB / RPB, FSPLIT), dim3(BT), 0, stream>>>(
        y, (const char*)d_ws, out);
}